// Round 1
// baseline (222.893 us; speedup 1.0000x reference)
//
#include <hip/hip_runtime.h>
#include <cmath>

// CNEncoder: the MCMC/graph-smoothing path cancels out of the output
// (final_states s enters as rf*s / (s*S + 1e-8) * P -> s-dependence is
// ~7e-12 relative). Remaining computation:
//   S_i = sum_j rf[i,j]; P_i = sum_j nx[i,j]; scale_i = P_i/(S_i+EPS)
//   t[i,j] = rf[i,j]*scale_i
//   tmin/tmax global; rmin=0.8*tmin, rmax=1.2*tmax
//   a=(rmax-rmin)/(tmax-tmin+EPS); mean_u = (mean_t - tmin)*a + rmin
//   out[i,j] = (t[i,j]*a + (rmin - tmin*a)) / mean_u = rf[i,j]*(scale_i*A) + B
//   reg_loss = sum(rf^2)*1e-4

static constexpr int NS = 20000;
static constexpr int NG = 3000;
static constexpr int G4 = NG / 4;       // 750 float4 per row; row stride 12000 B (16B aligned)
static constexpr float EPS = 1e-8f;

// ws layout (floats): [0,NS) S | [NS,2NS) P | [2NS,3NS) rowmin | [3NS,4NS) rowmax
//                     [4NS,5NS) rowssq | [5NS,5NS+2) {A,B}

__global__ __launch_bounds__(256) void k_rowstats(
    const float4* __restrict__ rf, const float4* __restrict__ nx,
    float* __restrict__ S, float* __restrict__ P,
    float* __restrict__ MN, float* __restrict__ MX, float* __restrict__ Q)
{
    const int row = blockIdx.x;
    const float4* r = rf + (size_t)row * G4;
    const float4* n = nx + (size_t)row * G4;
    float s = 0.f, p = 0.f, q = 0.f, mn = INFINITY, mx = -INFINITY;
    for (int c = threadIdx.x; c < G4; c += 256) {
        float4 a = r[c];
        float4 b = n[c];
        s += (a.x + a.y) + (a.z + a.w);
        q += a.x * a.x + a.y * a.y + a.z * a.z + a.w * a.w;
        mn = fminf(mn, fminf(fminf(a.x, a.y), fminf(a.z, a.w)));
        mx = fmaxf(mx, fmaxf(fmaxf(a.x, a.y), fmaxf(a.z, a.w)));
        p += (b.x + b.y) + (b.z + b.w);
    }
    #pragma unroll
    for (int off = 32; off > 0; off >>= 1) {
        s += __shfl_down(s, off);
        p += __shfl_down(p, off);
        q += __shfl_down(q, off);
        mn = fminf(mn, __shfl_down(mn, off));
        mx = fmaxf(mx, __shfl_down(mx, off));
    }
    __shared__ float ls[4], lp[4], lq[4], lmn[4], lmx[4];
    const int wid = threadIdx.x >> 6;
    if ((threadIdx.x & 63) == 0) { ls[wid] = s; lp[wid] = p; lq[wid] = q; lmn[wid] = mn; lmx[wid] = mx; }
    __syncthreads();
    if (threadIdx.x == 0) {
        s  = (ls[0] + ls[1]) + (ls[2] + ls[3]);
        p  = (lp[0] + lp[1]) + (lp[2] + lp[3]);
        q  = (lq[0] + lq[1]) + (lq[2] + lq[3]);
        mn = fminf(fminf(lmn[0], lmn[1]), fminf(lmn[2], lmn[3]));
        mx = fmaxf(fmaxf(lmx[0], lmx[1]), fmaxf(lmx[2], lmx[3]));
        S[row] = s; P[row] = p; Q[row] = q; MN[row] = mn; MX[row] = mx;
    }
}

__global__ __launch_bounds__(256) void k_scalars(
    const float* __restrict__ S, const float* __restrict__ P,
    const float* __restrict__ MN, const float* __restrict__ MX,
    const float* __restrict__ Q,
    float* __restrict__ AB, float* __restrict__ loss_out)
{
    double st = 0.0, sq = 0.0;
    float tmn = INFINITY, tmx = -INFINITY;
    for (int i = threadIdx.x; i < NS; i += 256) {
        const float sc = P[i] / (S[i] + EPS);
        st += (double)(sc * S[i]);
        sq += (double)Q[i];
        tmn = fminf(tmn, MN[i] * sc);
        tmx = fmaxf(tmx, MX[i] * sc);
    }
    #pragma unroll
    for (int off = 32; off > 0; off >>= 1) {
        st += __shfl_down(st, off);
        sq += __shfl_down(sq, off);
        tmn = fminf(tmn, __shfl_down(tmn, off));
        tmx = fmaxf(tmx, __shfl_down(tmx, off));
    }
    __shared__ double lst[4], lsq[4];
    __shared__ float lmn[4], lmx[4];
    const int wid = threadIdx.x >> 6;
    if ((threadIdx.x & 63) == 0) { lst[wid] = st; lsq[wid] = sq; lmn[wid] = tmn; lmx[wid] = tmx; }
    __syncthreads();
    if (threadIdx.x == 0) {
        st  = (lst[0] + lst[1]) + (lst[2] + lst[3]);
        sq  = (lsq[0] + lsq[1]) + (lsq[2] + lsq[3]);
        tmn = fminf(fminf(lmn[0], lmn[1]), fminf(lmn[2], lmn[3]));
        tmx = fmaxf(fmaxf(lmx[0], lmx[1]), fmaxf(lmx[2], lmx[3]));
        const float rmin = tmn * 0.8f;
        const float rmax = tmx * 1.2f;
        const float a = (rmax - rmin) / (tmx - tmn + EPS);
        const float mean_t = (float)(st / (double)((long long)NS * (long long)NG));
        const float mean_u = (mean_t - tmn) * a + rmin;
        AB[0] = a / mean_u;
        AB[1] = (rmin - tmn * a) / mean_u;
        *loss_out = (float)(sq * 1e-4);
    }
}

__global__ __launch_bounds__(256) void k_finalize(
    const float4* __restrict__ rf,
    const float* __restrict__ S, const float* __restrict__ P,
    const float* __restrict__ AB,
    float4* __restrict__ out)
{
    const int row = blockIdx.x;
    const float A = AB[0], B = AB[1];
    const float c = (P[row] / (S[row] + EPS)) * A;
    const float4* r = rf + (size_t)row * G4;
    float4* o = out + (size_t)row * G4;
    for (int i = threadIdx.x; i < G4; i += 256) {
        float4 a = r[i];
        float4 v;
        v.x = fmaf(a.x, c, B);
        v.y = fmaf(a.y, c, B);
        v.z = fmaf(a.z, c, B);
        v.w = fmaf(a.w, c, B);
        o[i] = v;
    }
}

extern "C" void kernel_launch(void* const* d_in, const int* in_sizes, int n_in,
                              void* d_out, int out_size, void* d_ws, size_t ws_size,
                              hipStream_t stream) {
    const float* nx = (const float*)d_in[0];   // norm_x (N_SPOTS x N_GENES)
    const float* rf = (const float*)d_in[1];   // reconstructed_features
    // d_in[2] (edge_index) is intentionally unused: its effect on the output
    // is below 1e-11 relative (see header comment).
    float* out = (float*)d_out;
    float* ws = (float*)d_ws;
    float* S  = ws;
    float* P  = ws + NS;
    float* MN = ws + 2 * NS;
    float* MX = ws + 3 * NS;
    float* Q  = ws + 4 * NS;
    float* AB = ws + 5 * NS;
    float* loss_out = out + (out_size - 1);    // reg_loss is the last flat element

    k_rowstats<<<NS, 256, 0, stream>>>((const float4*)rf, (const float4*)nx, S, P, MN, MX, Q);
    k_scalars<<<1, 256, 0, stream>>>(S, P, MN, MX, Q, AB, loss_out);
    k_finalize<<<NS, 256, 0, stream>>>((const float4*)rf, S, P, AB, (float4*)out);
}

// Round 3
// 161.088 us; speedup vs baseline: 1.3837x; 1.3837x over previous
//
#include <hip/hip_runtime.h>
#include <cmath>

// CNEncoder reduced form (MCMC/graph path cancels; see round-0 derivation):
//   P_i = sum_j nx[i,j]; S_i = sum_j rf[i,j]; scale_i = P_i/(S_i+EPS)
//   t = rf*scale; global tmin/tmax/mean -> affine out = rf*(scale_i*A)+B
//   reg_loss = sum(rf^2)*1e-4
//
// L3 choreography: nx is read with NT loads (evict-first), rf with normal
// loads (allocates in the 256MB L3), out written with NT stores (doesn't
// evict rf). Steady-state HBM traffic ~= nx read + out write = 480 MB.

static constexpr int NS = 20000;
static constexpr int NG = 3000;
static constexpr int G4 = NG / 4;       // 750 float4/row, row stride 12000 B
static constexpr float EPS = 1e-8f;

// native vector type: __builtin_nontemporal_* requires a pointer to a
// scalar or native vector, not HIP's HIP_vector_type class.
typedef float fv4 __attribute__((ext_vector_type(4)));

// ws floats: [0,NS) S | [NS,2NS) P | [2NS,3NS) MN | [3NS,4NS) MX | [4NS,5NS) Q | [5NS..) AB

// ---- pass A: per-row sum of norm_x, NT loads, one wave per row ----
__global__ __launch_bounds__(256) void k_p(const fv4* __restrict__ nx,
                                           float* __restrict__ P)
{
    const int row  = blockIdx.x * 4 + (threadIdx.x >> 6);
    const int lane = threadIdx.x & 63;
    const fv4* n = nx + (size_t)row * G4;
    float p = 0.f;
    for (int c = lane; c < G4; c += 64) {
        fv4 b = __builtin_nontemporal_load(n + c);
        p += (b.x + b.y) + (b.z + b.w);
    }
    #pragma unroll
    for (int off = 32; off > 0; off >>= 1) p += __shfl_down(p, off);
    if (lane == 0) P[row] = p;
}

// ---- pass B: per-row stats of rf, normal loads (allocate in L3) ----
__global__ __launch_bounds__(256) void k_rfstats(const fv4* __restrict__ rf,
                                                 float* __restrict__ S,
                                                 float* __restrict__ MN,
                                                 float* __restrict__ MX,
                                                 float* __restrict__ Q)
{
    const int row  = blockIdx.x * 4 + (threadIdx.x >> 6);
    const int lane = threadIdx.x & 63;
    const fv4* r = rf + (size_t)row * G4;
    float s = 0.f, q = 0.f, mn = INFINITY, mx = -INFINITY;
    for (int c = lane; c < G4; c += 64) {
        fv4 a = r[c];
        s += (a.x + a.y) + (a.z + a.w);
        q += a.x * a.x + a.y * a.y + a.z * a.z + a.w * a.w;
        mn = fminf(mn, fminf(fminf(a.x, a.y), fminf(a.z, a.w)));
        mx = fmaxf(mx, fmaxf(fmaxf(a.x, a.y), fmaxf(a.z, a.w)));
    }
    #pragma unroll
    for (int off = 32; off > 0; off >>= 1) {
        s += __shfl_down(s, off);
        q += __shfl_down(q, off);
        mn = fminf(mn, __shfl_down(mn, off));
        mx = fmaxf(mx, __shfl_down(mx, off));
    }
    if (lane == 0) { S[row] = s; Q[row] = q; MN[row] = mn; MX[row] = mx; }
}

// ---- scalars: fold 5*NS row stats into {A,B} and reg_loss ----
__global__ __launch_bounds__(256) void k_scalars(
    const fv4* __restrict__ S4, const fv4* __restrict__ P4,
    const fv4* __restrict__ MN4, const fv4* __restrict__ MX4,
    const fv4* __restrict__ Q4,
    float* __restrict__ AB, float* __restrict__ loss_out)
{
    double st = 0.0, sq = 0.0;
    float tmn = INFINITY, tmx = -INFINITY;
    for (int i = threadIdx.x; i < NS / 4; i += 256) {
        fv4 s = S4[i], p = P4[i], mn = MN4[i], mx = MX4[i], q = Q4[i];
        float sc0 = p.x / (s.x + EPS), sc1 = p.y / (s.y + EPS);
        float sc2 = p.z / (s.z + EPS), sc3 = p.w / (s.w + EPS);
        st += (double)(sc0 * s.x) + (double)(sc1 * s.y)
            + (double)(sc2 * s.z) + (double)(sc3 * s.w);
        sq += (double)q.x + (double)q.y + (double)q.z + (double)q.w;
        tmn = fminf(tmn, fminf(fminf(mn.x * sc0, mn.y * sc1), fminf(mn.z * sc2, mn.w * sc3)));
        tmx = fmaxf(tmx, fmaxf(fmaxf(mx.x * sc0, mx.y * sc1), fmaxf(mx.z * sc2, mx.w * sc3)));
    }
    #pragma unroll
    for (int off = 32; off > 0; off >>= 1) {
        st += __shfl_down(st, off);
        sq += __shfl_down(sq, off);
        tmn = fminf(tmn, __shfl_down(tmn, off));
        tmx = fmaxf(tmx, __shfl_down(tmx, off));
    }
    __shared__ double lst[4], lsq[4];
    __shared__ float lmn[4], lmx[4];
    const int wid = threadIdx.x >> 6;
    if ((threadIdx.x & 63) == 0) { lst[wid] = st; lsq[wid] = sq; lmn[wid] = tmn; lmx[wid] = tmx; }
    __syncthreads();
    if (threadIdx.x == 0) {
        st  = (lst[0] + lst[1]) + (lst[2] + lst[3]);
        sq  = (lsq[0] + lsq[1]) + (lsq[2] + lsq[3]);
        tmn = fminf(fminf(lmn[0], lmn[1]), fminf(lmn[2], lmn[3]));
        tmx = fmaxf(fmaxf(lmx[0], lmx[1]), fmaxf(lmx[2], lmx[3]));
        const float rmin = tmn * 0.8f;
        const float rmax = tmx * 1.2f;
        const float a = (rmax - rmin) / (tmx - tmn + EPS);
        const float mean_t = (float)(st / (double)((long long)NS * (long long)NG));
        const float mean_u = (mean_t - tmn) * a + rmin;
        AB[0] = a / mean_u;
        AB[1] = (rmin - tmn * a) / mean_u;
        *loss_out = (float)(sq * 1e-4);
    }
}

// ---- pass C: out = rf*c_row + B; rf reads hit L3, NT stores for out ----
__global__ __launch_bounds__(256) void k_finalize(
    const fv4* __restrict__ rf,
    const float* __restrict__ S, const float* __restrict__ P,
    const float* __restrict__ AB,
    fv4* __restrict__ out)
{
    const int row = blockIdx.x;
    const float A = AB[0], B = AB[1];
    const float c = (P[row] / (S[row] + EPS)) * A;
    const fv4* r = rf + (size_t)row * G4;
    fv4* o = out + (size_t)row * G4;
    for (int i = threadIdx.x; i < G4; i += 256) {
        fv4 a = r[i];
        fv4 v;
        v.x = fmaf(a.x, c, B);
        v.y = fmaf(a.y, c, B);
        v.z = fmaf(a.z, c, B);
        v.w = fmaf(a.w, c, B);
        __builtin_nontemporal_store(v, o + i);
    }
}

extern "C" void kernel_launch(void* const* d_in, const int* in_sizes, int n_in,
                              void* d_out, int out_size, void* d_ws, size_t ws_size,
                              hipStream_t stream) {
    const float* nx = (const float*)d_in[0];   // norm_x
    const float* rf = (const float*)d_in[1];   // reconstructed_features
    // d_in[2] (edge_index) unused: effect on output < 1e-11 relative.
    float* out = (float*)d_out;
    float* ws = (float*)d_ws;
    float* S  = ws;
    float* P  = ws + NS;
    float* MN = ws + 2 * NS;
    float* MX = ws + 3 * NS;
    float* Q  = ws + 4 * NS;
    float* AB = ws + 5 * NS;
    float* loss_out = out + (out_size - 1);

    k_p      <<<NS / 4, 256, 0, stream>>>((const fv4*)nx, P);
    k_rfstats<<<NS / 4, 256, 0, stream>>>((const fv4*)rf, S, MN, MX, Q);
    k_scalars<<<1, 256, 0, stream>>>((const fv4*)S, (const fv4*)P,
                                     (const fv4*)MN, (const fv4*)MX,
                                     (const fv4*)Q, AB, loss_out);
    k_finalize<<<NS, 256, 0, stream>>>((const fv4*)rf, S, P, AB, (fv4*)out);
}

// Round 5
// 150.720 us; speedup vs baseline: 1.4789x; 1.0688x over previous
//
#include <hip/hip_runtime.h>
#include <cmath>

// CNEncoder reduced form (MCMC/graph path cancels; see round-0 derivation):
//   P_i = sum_j nx[i,j]; S_i = sum_j rf[i,j]; scale_i = P_i/(S_i+EPS)
//   t = rf*scale; global tmin/tmax/mean -> affine out = rf*(scale_i*A)+B
//   reg_loss = sum(rf^2)*1e-4
//
// Structure: one fused stats pass (nx NT-loads, rf normal loads -> L3),
// a 20KB two-stage scalar reduce, and a finalize pass (rf reads L3-hot,
// NT stores for out). Steady-state HBM traffic ~ nx + rf + out = 720 MB.

static constexpr int NS = 20000;
static constexpr int NG = 3000;
static constexpr int G4 = NG / 4;        // 750 float4/row, row stride 12000 B
static constexpr int NW = NS / 4;        // 5000 waves, 4 rows per wave
static constexpr int NB = NW / 4;        // 1250 blocks (4 waves each)
static constexpr float EPS = 1e-8f;

typedef float fv4 __attribute__((ext_vector_type(4)));

// ws floats: [0,NS) S | [NS,2NS) P |
//            [2NS, 2NS+NB) PST | +NB PSQ | +2NB PMN | +3NB PMX | then AB[2]

// ---- pass 1: per-row stats of both arrays + block partials ----
__global__ __launch_bounds__(256) void k_stats(
    const fv4* __restrict__ nx, const fv4* __restrict__ rf,
    float* __restrict__ S, float* __restrict__ P,
    float* __restrict__ PST, float* __restrict__ PSQ,
    float* __restrict__ PMN, float* __restrict__ PMX)
{
    const int wid  = threadIdx.x >> 6;
    const int lane = threadIdx.x & 63;
    const int gw   = blockIdx.x * 4 + wid;       // 0..NW-1
    float st = 0.f, sq = 0.f, tmn = INFINITY, tmx = -INFINITY;
    #pragma unroll
    for (int k = 0; k < 4; ++k) {
        const int row = gw + k * NW;
        const fv4* r = rf + (size_t)row * G4;
        const fv4* n = nx + (size_t)row * G4;
        float s = 0.f, p = 0.f, q = 0.f, mn = INFINITY, mx = -INFINITY;
        for (int c = lane; c < G4; c += 64) {
            fv4 a = r[c];
            fv4 b = __builtin_nontemporal_load(n + c);
            s += (a.x + a.y) + (a.z + a.w);
            q += a.x * a.x + a.y * a.y + a.z * a.z + a.w * a.w;
            mn = fminf(mn, fminf(fminf(a.x, a.y), fminf(a.z, a.w)));
            mx = fmaxf(mx, fmaxf(fmaxf(a.x, a.y), fmaxf(a.z, a.w)));
            p += (b.x + b.y) + (b.z + b.w);
        }
        #pragma unroll
        for (int off = 32; off > 0; off >>= 1) {
            s += __shfl_down(s, off);
            p += __shfl_down(p, off);
            q += __shfl_down(q, off);
            mn = fminf(mn, __shfl_down(mn, off));
            mx = fmaxf(mx, __shfl_down(mx, off));
        }
        if (lane == 0) {
            S[row] = s; P[row] = p;
            const float sc = p / (s + EPS);
            st += sc * s;
            sq += q;
            tmn = fminf(tmn, mn * sc);
            tmx = fmaxf(tmx, mx * sc);
        }
    }
    __shared__ float lst[4], lsq[4], lmn[4], lmx[4];
    if (lane == 0) { lst[wid] = st; lsq[wid] = sq; lmn[wid] = tmn; lmx[wid] = tmx; }
    __syncthreads();
    if (threadIdx.x == 0) {
        PST[blockIdx.x] = (lst[0] + lst[1]) + (lst[2] + lst[3]);
        PSQ[blockIdx.x] = (lsq[0] + lsq[1]) + (lsq[2] + lsq[3]);
        PMN[blockIdx.x] = fminf(fminf(lmn[0], lmn[1]), fminf(lmn[2], lmn[3]));
        PMX[blockIdx.x] = fmaxf(fmaxf(lmx[0], lmx[1]), fmaxf(lmx[2], lmx[3]));
    }
}

// ---- pass 2: fold 1250 block partials into {A,B} and reg_loss ----
__global__ __launch_bounds__(256) void k_scalars(
    const float* __restrict__ PST, const float* __restrict__ PSQ,
    const float* __restrict__ PMN, const float* __restrict__ PMX,
    float* __restrict__ AB, float* __restrict__ loss_out)
{
    double st = 0.0, sq = 0.0;
    float tmn = INFINITY, tmx = -INFINITY;
    for (int i = threadIdx.x; i < NB; i += 256) {
        st += (double)PST[i];
        sq += (double)PSQ[i];
        tmn = fminf(tmn, PMN[i]);
        tmx = fmaxf(tmx, PMX[i]);
    }
    #pragma unroll
    for (int off = 32; off > 0; off >>= 1) {
        st += __shfl_down(st, off);
        sq += __shfl_down(sq, off);
        tmn = fminf(tmn, __shfl_down(tmn, off));
        tmx = fmaxf(tmx, __shfl_down(tmx, off));
    }
    __shared__ double lst[4], lsq[4];
    __shared__ float lmn[4], lmx[4];
    const int wid = threadIdx.x >> 6;
    if ((threadIdx.x & 63) == 0) { lst[wid] = st; lsq[wid] = sq; lmn[wid] = tmn; lmx[wid] = tmx; }
    __syncthreads();
    if (threadIdx.x == 0) {
        st  = (lst[0] + lst[1]) + (lst[2] + lst[3]);
        sq  = (lsq[0] + lsq[1]) + (lsq[2] + lsq[3]);
        tmn = fminf(fminf(lmn[0], lmn[1]), fminf(lmn[2], lmn[3]));
        tmx = fmaxf(fmaxf(lmx[0], lmx[1]), fmaxf(lmx[2], lmx[3]));
        const float rmin = tmn * 0.8f;
        const float rmax = tmx * 1.2f;
        const float a = (rmax - rmin) / (tmx - tmn + EPS);
        const float mean_t = (float)(st / (double)((long long)NS * (long long)NG));
        const float mean_u = (mean_t - tmn) * a + rmin;
        AB[0] = a / mean_u;
        AB[1] = (rmin - tmn * a) / mean_u;
        *loss_out = (float)(sq * 1e-4);
    }
}

// ---- pass 3: out = rf*c_row + B; wave per row; NT stores ----
__global__ __launch_bounds__(256) void k_finalize(
    const fv4* __restrict__ rf,
    const float* __restrict__ S, const float* __restrict__ P,
    const float* __restrict__ AB,
    fv4* __restrict__ out)
{
    const int row  = blockIdx.x * 4 + (threadIdx.x >> 6);
    const int lane = threadIdx.x & 63;
    const float A = AB[0], B = AB[1];
    const float c = (P[row] / (S[row] + EPS)) * A;
    const fv4* r = rf + (size_t)row * G4;
    fv4* o = out + (size_t)row * G4;
    for (int i = lane; i < G4; i += 64) {
        fv4 a = r[i];
        fv4 v;
        v.x = fmaf(a.x, c, B);
        v.y = fmaf(a.y, c, B);
        v.z = fmaf(a.z, c, B);
        v.w = fmaf(a.w, c, B);
        __builtin_nontemporal_store(v, o + i);
    }
}

extern "C" void kernel_launch(void* const* d_in, const int* in_sizes, int n_in,
                              void* d_out, int out_size, void* d_ws, size_t ws_size,
                              hipStream_t stream) {
    const float* nx = (const float*)d_in[0];   // norm_x
    const float* rf = (const float*)d_in[1];   // reconstructed_features
    // d_in[2] (edge_index) unused: effect on output < 1e-11 relative.
    float* out = (float*)d_out;
    float* ws  = (float*)d_ws;
    float* S   = ws;
    float* P   = ws + NS;
    float* PST = ws + 2 * NS;
    float* PSQ = PST + NB;
    float* PMN = PST + 2 * NB;
    float* PMX = PST + 3 * NB;
    float* AB  = PST + 4 * NB;
    float* loss_out = out + (out_size - 1);

    k_stats   <<<NB,     256, 0, stream>>>((const fv4*)nx, (const fv4*)rf,
                                           S, P, PST, PSQ, PMN, PMX);
    k_scalars <<<1,      256, 0, stream>>>(PST, PSQ, PMN, PMX, AB, loss_out);
    k_finalize<<<NS / 4, 256, 0, stream>>>((const fv4*)rf, S, P, AB, (fv4*)out);
}